// Round 10
// baseline (945.225 us; speedup 1.0000x reference)
//
#include <hip/hip_runtime.h>

#define LL 13
#define BB 32
#define NN 512
#define HH 768
#define MM 384
#define EE 768
#define BN (BB*NN)   // 16384
#define K12 (12*NN)  // 6144

typedef __attribute__((ext_vector_type(8))) short s16x8;
typedef __attribute__((ext_vector_type(4))) float f32x4;
typedef __attribute__((ext_vector_type(4))) unsigned int u32x4;
typedef unsigned int u32;
#define AS1 __attribute__((address_space(1)))
#define AS3 __attribute__((address_space(3)))

// hardware packed fp32->bf16 (RNE), gfx950
__device__ __forceinline__ u32 cvtpk2(float a, float b) {
    u32 r; asm("v_cvt_pk_bf16_f32 %0, %1, %2" : "=v"(r) : "v"(a), "v"(b));
    return r;
}
__device__ __forceinline__ short f2bf_hw(float f) {
    u32 r; asm("v_cvt_pk_bf16_f32 %0, %1, %2" : "=v"(r) : "v"(f), "v"(f));
    return (short)r;
}
__device__ __forceinline__ float bf2f(short h) {
    union { u32 u; float f; } c; c.u = ((u32)(unsigned short)h) << 16;
    return c.f;
}
__device__ __forceinline__ void gload16(const void* g, void* l) {
    __builtin_amdgcn_global_load_lds((const AS1 u32*)g, (AS3 u32*)l, 16, 0, 0);
}

// ============ bf16 MFMA GEMM core: 128x128 tile, BK=32, 4 waves, 16x16x32 ============
// C(128x128) = A(128xK) * B^T(128xK), both operands reduction-contiguous.
// AM=0: A bf16 via global_load_lds. AM=2: A = fp32(At)+fp32(At2), reg-staged + cvt.
// 2-phase double-buffered pipeline (R8-proven), one __syncthreads per K-step.
template<int AM>
__device__ __forceinline__ void gemm_core(const char* At, const char* At2, int lda,
                                          const char* Bt, int ldb,
                                          int K, char* lds, f32x4 acc[4][4])
{
    const int tid  = threadIdx.x;
    const int lane = tid & 63;
    const int w    = tid >> 6;
    const int mt0 = (w >> 1) * 4;
    const int nt0 = (w & 1) * 4;

    const int rg0 = (w*2)*16 + (lane & 15);
    const int rg1 = rg0 + 16;
    const int kcb = (lane >> 4) * 16;
    const char* gb0 = Bt + (size_t)rg0 * ldb * 2 + kcb;
    const char* gb1 = Bt + (size_t)rg1 * ldb * 2 + kcb;
    const int lboff0 = 8192 + (w*2)*1024;
    const int lboff1 = lboff0 + 1024;

    auto mfma_step = [&](int bo) {
        s16x8 af[4], bf4[4];
        char* sA = lds + bo;
        char* sB = sA + 8192;
        #pragma unroll
        for (int i = 0; i < 4; ++i) af[i] = *(const s16x8*)(sA + ((mt0+i)<<10) + lane*16);
        #pragma unroll
        for (int j = 0; j < 4; ++j) bf4[j] = *(const s16x8*)(sB + ((nt0+j)<<10) + lane*16);
        #pragma unroll
        for (int i = 0; i < 4; ++i)
            #pragma unroll
            for (int j = 0; j < 4; ++j)
                acc[i][j] = __builtin_amdgcn_mfma_f32_16x16x32_bf16(af[i], bf4[j], acc[i][j], 0, 0, 0);
    };

    if (AM == 0) {
        const char* ga0 = At + (size_t)rg0 * lda * 2 + kcb;
        const char* ga1 = At + (size_t)rg1 * lda * 2 + kcb;
        const int laoff0 = (w*2)*1024, laoff1 = laoff0 + 1024;
        gload16(ga0, lds + laoff0); gload16(ga1, lds + laoff1);
        gload16(gb0, lds + lboff0); gload16(gb1, lds + lboff1);
        ga0 += 64; ga1 += 64; gb0 += 64; gb1 += 64;
        __syncthreads();
        int bo = 0;
        for (int k0 = 32; k0 < K; k0 += 32) {
            const int nbo = bo ^ 16384;
            gload16(ga0, lds + nbo + laoff0); gload16(ga1, lds + nbo + laoff1);
            gload16(gb0, lds + nbo + lboff0); gload16(gb1, lds + nbo + lboff1);
            ga0 += 64; ga1 += 64; gb0 += 64; gb1 += 64;
            mfma_step(bo);
            __syncthreads();
            bo = nbo;
        }
        mfma_step(bo);
    } else {
        size_t goff_[4]; int loff_[4];
        #pragma unroll
        for (int c = 0; c < 4; ++c) {
            int id = c*256 + tid;
            int row = id >> 3, c16 = id & 7;
            goff_[c] = (size_t)row * lda * 4 + c16 * 16;
            loff_[c] = ((row>>4)*64 + (row&15) + (c16>>1)*16)*16 + (c16&1)*8;
        }
        f32x4 g[4];
        #pragma unroll
        for (int c = 0; c < 4; ++c) {
            g[c] = *(const f32x4*)(At + goff_[c]);
            f32x4 h = *(const f32x4*)(At2 + goff_[c]);
            g[c][0]+=h[0]; g[c][1]+=h[1]; g[c][2]+=h[2]; g[c][3]+=h[3];
        }
        gload16(gb0, lds + lboff0); gload16(gb1, lds + lboff1);
        gb0 += 64; gb1 += 64;
        #pragma unroll
        for (int c = 0; c < 4; ++c) {
            u32* d = (u32*)(lds + loff_[c]);
            d[0] = cvtpk2(g[c][0], g[c][1]);
            d[1] = cvtpk2(g[c][2], g[c][3]);
        }
        __syncthreads();
        int bo = 0;
        size_t kb = 128;
        for (int k0 = 32; k0 < K; k0 += 32, kb += 128) {
            const int nbo = bo ^ 16384;
            #pragma unroll
            for (int c = 0; c < 4; ++c) {
                g[c] = *(const f32x4*)(At + goff_[c] + kb);
                f32x4 h = *(const f32x4*)(At2 + goff_[c] + kb);
                g[c][0]+=h[0]; g[c][1]+=h[1]; g[c][2]+=h[2]; g[c][3]+=h[3];
            }
            gload16(gb0, lds + nbo + lboff0); gload16(gb1, lds + nbo + lboff1);
            gb0 += 64; gb1 += 64;
            mfma_step(bo);
            #pragma unroll
            for (int c = 0; c < 4; ++c) {
                u32* d = (u32*)(lds + nbo + loff_[c]);
                d[0] = cvtpk2(g[c][0], g[c][1]);
                d[1] = cvtpk2(g[c][2], g[c][3]);
            }
            __syncthreads();
            bo = nbo;
        }
        mfma_step(bo);
    }
}

__device__ __forceinline__ void zero_acc(f32x4 acc[4][4]) {
    #pragma unroll
    for (int i = 0; i < 4; ++i)
        #pragma unroll
        for (int j = 0; j < 4; ++j) {
            acc[i][j][0] = 0.f; acc[i][j][1] = 0.f;
            acc[i][j][2] = 0.f; acc[i][j][3] = 0.f;
        }
}

// ---------------- K_zero: clear raw-sum accumulators ----------------
__global__ __launch_bounds__(256) void k_zero(float* __restrict__ p, int n4)
{
    int i = blockIdx.x*256 + threadIdx.x;
    if (i < n4) { f32x4 z = {0.f,0.f,0.f,0.f}; ((f32x4*)p)[i] = z; }
}

// ---------------- K0: weight transpose fp32[R][C] -> bf16[C][R] ----------------
__global__ __launch_bounds__(256) void k_wt(const float* __restrict__ in, short* __restrict__ out,
                                            int R, int C, size_t zin, size_t zout)
{
    __shared__ short L[64][80];
    const float* I = in + (size_t)blockIdx.z * zin;
    short* O = out + (size_t)blockIdx.z * zout;
    const int r0 = blockIdx.y * 64, c0 = blockIdx.x * 64;
    const int t = threadIdx.x;
    {
        int r = t >> 2, cq = (t & 3) * 16;
        const float* p = I + (size_t)(r0 + r) * C + c0 + cq;
        f32x4 u0 = *(const f32x4*)(p);
        f32x4 u1 = *(const f32x4*)(p + 4);
        f32x4 u2 = *(const f32x4*)(p + 8);
        f32x4 u3 = *(const f32x4*)(p + 12);
        u32x4 pa, pb;
        pa[0]=cvtpk2(u0[0],u0[1]); pa[1]=cvtpk2(u0[2],u0[3]);
        pa[2]=cvtpk2(u1[0],u1[1]); pa[3]=cvtpk2(u1[2],u1[3]);
        pb[0]=cvtpk2(u2[0],u2[1]); pb[1]=cvtpk2(u2[2],u2[3]);
        pb[2]=cvtpk2(u3[0],u3[1]); pb[3]=cvtpk2(u3[2],u3[3]);
        *(u32x4*)&L[r][cq]     = pa;
        *(u32x4*)&L[r][cq + 8] = pb;
    }
    __syncthreads();
    #pragma unroll
    for (int it = 0; it < 2; ++it) {
        int id = it * 256 + t;
        int cc = id >> 3, rq = id & 7;
        s16x8 v;
        #pragma unroll
        for (int e = 0; e < 8; ++e) v[e] = L[rq*8 + e][cc];
        *(s16x8*)(O + (size_t)(c0 + cc) * R + r0 + rq*8) = v;
    }
}

// ---------------- K1: down GEMM, 128x384 full-M tile (X read ONCE), 512 thr / 8 waves ----------------
// Waves: 2 row-groups (wr) x 4 col-groups (wcg); per wave 64 rows x 96 cols, acc[4][6].
// LDS per buffer: A 8K (fp32 reg-staged + cvt_pk), B 24K (gload_lds); dbuf = 64K; ep reuse 72K.
__global__ __launch_bounds__(512) void k_down(const float* __restrict__ X,
                                              const short* __restrict__ WdT,
                                              const float* __restrict__ bd,
                                              short* __restrict__ down)
{
    __shared__ char lds[73728];
    const int lg = ((blockIdx.x & 7) * 208) + (blockIdx.x >> 3);   // XCD-chunked swizzle (1664=8*208)
    const int rowtile = lg & 127;
    const int l = lg >> 7;
    const int tid = threadIdx.x, lane = tid & 63, w = tid >> 6;
    const int wr = w >> 2, wcg = w & 3;

    const char* Ab = (const char*)(X + ((size_t)l*BN + rowtile*128)*HH);
    const char* Bb = (const char*)(WdT + (size_t)l*MM*HH);

    // B staging: 24 groups of 16 rows; wave stages gidx = w*3..w*3+2
    const char* gp[3]; int lo[3];
    #pragma unroll
    for (int q = 0; q < 3; ++q) {
        int gidx = w*3 + q;
        gp[q] = Bb + (size_t)(gidx*16 + (lane & 15)) * HH * 2 + (lane >> 4)*16;
        lo[q] = 8192 + gidx*1024 + lane*16;
    }
    // A staging: 128 rows x 32 k fp32 = 1024 x 16B chunks; 2 per thread
    size_t goff_[2]; int loff_[2];
    #pragma unroll
    for (int c = 0; c < 2; ++c) {
        int id = c*512 + tid;
        int row = id >> 3, c16 = id & 7;
        goff_[c] = (size_t)row * HH * 4 + c16 * 16;
        loff_[c] = ((row>>4)*64 + (row&15) + (c16>>1)*16)*16 + (c16&1)*8;
    }

    f32x4 acc[4][6];
    #pragma unroll
    for (int i = 0; i < 4; ++i)
        #pragma unroll
        for (int j = 0; j < 6; ++j) { acc[i][j][0]=0.f; acc[i][j][1]=0.f; acc[i][j][2]=0.f; acc[i][j][3]=0.f; }

    auto mfma_step = [&](int bo) {
        s16x8 af[4], bf4[6];
        #pragma unroll
        for (int i = 0; i < 4; ++i) af[i] = *(const s16x8*)(lds + bo + ((wr*4 + i)<<10) + lane*16);
        #pragma unroll
        for (int j = 0; j < 6; ++j) bf4[j] = *(const s16x8*)(lds + bo + 8192 + ((wcg*6 + j)<<10) + lane*16);
        #pragma unroll
        for (int i = 0; i < 4; ++i)
            #pragma unroll
            for (int j = 0; j < 6; ++j)
                acc[i][j] = __builtin_amdgcn_mfma_f32_16x16x32_bf16(af[i], bf4[j], acc[i][j], 0, 0, 0);
    };

    // prologue: stage k-step 0 into buf0
    f32x4 gA[2];
    #pragma unroll
    for (int c = 0; c < 2; ++c) gA[c] = *(const f32x4*)(Ab + goff_[c]);
    #pragma unroll
    for (int q = 0; q < 3; ++q) { gload16(gp[q], lds + lo[q]); gp[q] += 64; }
    #pragma unroll
    for (int c = 0; c < 2; ++c) {
        u32* d = (u32*)(lds + loff_[c]);
        d[0] = cvtpk2(gA[c][0], gA[c][1]);
        d[1] = cvtpk2(gA[c][2], gA[c][3]);
    }
    __syncthreads();
    int bo = 0;
    size_t kb = 128;
    for (int k0 = 32; k0 < HH; k0 += 32, kb += 128) {
        const int nbo = bo ^ 32768;
        #pragma unroll
        for (int c = 0; c < 2; ++c) gA[c] = *(const f32x4*)(Ab + goff_[c] + kb);
        #pragma unroll
        for (int q = 0; q < 3; ++q) { gload16(gp[q], lds + nbo + lo[q]); gp[q] += 64; }
        mfma_step(bo);
        #pragma unroll
        for (int c = 0; c < 2; ++c) {
            u32* d = (u32*)(lds + nbo + loff_[c]);
            d[0] = cvtpk2(gA[c][0], gA[c][1]);
            d[1] = cvtpk2(gA[c][2], gA[c][3]);
        }
        __syncthreads();
        bo = nbo;
    }
    mfma_step(bo);

    // ---- epilogue: bias + bf16 + per-wave transpose stores (64-col pass, then 32-col pass) ----
    float bj[6];
    #pragma unroll
    for (int j = 0; j < 6; ++j) bj[j] = bd[l*MM + wcg*96 + j*16 + (lane & 15)];
    __syncthreads();   // all waves done reading staging LDS before ep overwrite
    short* ep = (short*)(lds + w * 9216);
    short* C = down + ((size_t)l*BN + rowtile*128 + wr*64)*MM + wcg*96;
    // pass A: cols 0..63 (j = 0..3), ep stride 72
    #pragma unroll
    for (int i = 0; i < 4; ++i) {
        int rr = i*16 + (lane >> 4) * 4;
        #pragma unroll
        for (int j = 0; j < 4; ++j) {
            int cc = j*16 + (lane & 15);
            #pragma unroll
            for (int r = 0; r < 4; ++r)
                ep[(rr + r)*72 + cc] = f2bf_hw(acc[i][j][r] + bj[j]);
        }
    }
    __syncthreads();
    #pragma unroll
    for (int it = 0; it < 8; ++it) {
        int cdx = it*64 + lane;
        int row = cdx >> 3, kq = cdx & 7;
        s16x8 v = *(const s16x8*)(ep + row*72 + kq*8);
        *(s16x8*)(C + (size_t)row*MM + kq*8) = v;
    }
    __syncthreads();
    // pass B: cols 64..95 (j = 4..5), ep stride 40
    #pragma unroll
    for (int i = 0; i < 4; ++i) {
        int rr = i*16 + (lane >> 4) * 4;
        #pragma unroll
        for (int j = 4; j < 6; ++j) {
            int cc = (j-4)*16 + (lane & 15);
            #pragma unroll
            for (int r = 0; r < 4; ++r)
                ep[(rr + r)*40 + cc] = f2bf_hw(acc[i][j][r] + bj[j]);
        }
    }
    __syncthreads();
    #pragma unroll
    for (int it = 0; it < 4; ++it) {
        int cdx = it*64 + lane;
        int row = cdx >> 2, kq = cdx & 3;
        s16x8 v = *(const s16x8*)(ep + row*40 + kq*8);
        *(s16x8*)(C + (size_t)row*MM + 64 + kq*8) = v;
    }
}

// ---------------- K2: LN in place + transposed copy + fused masked-mean raw sums ----------------
__global__ __launch_bounds__(256) void k_ln(short* __restrict__ down,
                                            const float* __restrict__ g,
                                            const float* __restrict__ beta,
                                            short* __restrict__ downTb,
                                            const int* __restrict__ lengths,
                                            float* __restrict__ t_raw,
                                            float* __restrict__ a_raw)
{
    __shared__ short Lt[64][392];
    __shared__ float sacc[4][384];
    const int blk = blockIdx.x;
    const int l = blk / (BB*8);
    const int rem = blk % (BB*8);
    const int b = rem >> 3;
    const int n0 = (rem & 7) * 64;
    const int tid = threadIdx.x, lane = tid & 63, w = tid >> 6;
    const int len = lengths[b];
    float racc[6] = {0.f,0.f,0.f,0.f,0.f,0.f};

    for (int it = 0; it < 16; ++it) {
        int ri = it*4 + w;
        int n = n0 + ri;
        short* p = down + (((size_t)l*BB + b)*NN + n) * MM;
        u32* pu = (u32*)p;
        float f[6]; float s = 0.f, s2 = 0.f;
        #pragma unroll
        for (int t = 0; t < 3; ++t) {
            u32 q = pu[lane + t*64];
            float lo = bf2f((short)(q & 0xffff));
            float hi = bf2f((short)(q >> 16));
            f[2*t] = lo; f[2*t+1] = hi;
            s += lo + hi; s2 += lo*lo + hi*hi;
        }
        #pragma unroll
        for (int off = 32; off; off >>= 1) { s += __shfl_xor(s, off); s2 += __shfl_xor(s2, off); }
        float mu  = s * (1.f/MM);
        float inv = rsqrtf(s2 * (1.f/MM) - mu*mu + 1e-5f);
        const bool valid = n < len;
        #pragma unroll
        for (int t = 0; t < 3; ++t) {
            int m0 = (lane + t*64) * 2;
            float o0 = (f[2*t]  -mu)*inv * g[l*MM + m0]     + beta[l*MM + m0];
            float o1 = (f[2*t+1]-mu)*inv * g[l*MM + m0 + 1] + beta[l*MM + m0 + 1];
            u32 pk = cvtpk2(o0, o1);
            pu[lane + t*64] = pk;
            ((u32*)&Lt[ri][0])[lane + t*64] = pk;
            if (valid) { racc[2*t] += o0; racc[2*t+1] += o1; }
        }
    }
    #pragma unroll
    for (int t = 0; t < 3; ++t) {
        int m0 = (lane + t*64) * 2;
        sacc[w][m0]     = racc[2*t];
        sacc[w][m0 + 1] = racc[2*t+1];
    }
    __syncthreads();
    if (w == 0) {
        float* dst = (l == 12) ? (a_raw + b*MM) : (t_raw + ((size_t)l*BB + b)*MM);
        #pragma unroll
        for (int t = 0; t < 3; ++t) {
            #pragma unroll
            for (int e = 0; e < 2; ++e) {
                int m = (lane + t*64)*2 + e;
                float tot = sacc[0][m] + sacc[1][m] + sacc[2][m] + sacc[3][m];
                atomicAdd(&dst[m], tot);
            }
        }
    }
    if (l == 12) return;
    short* O = downTb + ((size_t)b*MM*12 + l) * NN;   // + m*12*NN + n
    #pragma unroll
    for (int it = 0; it < 12; ++it) {
        int id = it*256 + tid;
        int m = id >> 3, nq = id & 7;
        s16x8 vv;
        #pragma unroll
        for (int e = 0; e < 8; ++e) vv[e] = Lt[nq*8 + e][m];
        *(s16x8*)(O + (size_t)m*12*NN + n0 + nq*8) = vv;
    }
}

// ---------------- K4: conf from raw sums (1/len^2 folded) + lengths tail ----------------
__global__ __launch_bounds__(64) void k_conf(const float* __restrict__ a_raw,
                                             const float* __restrict__ t_raw,
                                             const float* __restrict__ Wg,
                                             const float* __restrict__ bg,
                                             const int* __restrict__ lengths,
                                             float* __restrict__ conf,
                                             float* __restrict__ out)
{
    const int b = blockIdx.x;
    const int lane = threadIdx.x;
    const float len = (float)lengths[b];
    const float inv2 = 1.f/(len*len);
    float lg[12];
    #pragma unroll
    for (int l = 0; l < 12; ++l) {
        float s = 0.f;
        #pragma unroll
        for (int t = 0; t < 6; ++t) {
            int m = lane + t*64;
            s += a_raw[b*MM + m] * t_raw[((size_t)l*BB + b)*MM + m] * Wg[m];
        }
        #pragma unroll
        for (int off = 32; off; off >>= 1) s += __shfl_xor(s, off);
        lg[l] = s * inv2 + bg[0];
    }
    float mx = lg[0];
    #pragma unroll
    for (int l = 1; l < 12; ++l) mx = fmaxf(mx, lg[l]);
    float den = 0.f, e[12];
    #pragma unroll
    for (int l = 0; l < 12; ++l) { e[l] = expf(lg[l]-mx); den += e[l]; }
    if (lane == 0) {
        #pragma unroll
        for (int l = 0; l < 12; ++l) conf[b*12 + l] = e[l]/den;
        out[(size_t)BB*NN*EE + b] = len;   // lengths tail
    }
}

// ---------------- K5: fused S row-block (dbuf K-loop, full-column store) ----------------
__global__ __launch_bounds__(512) void k_srow(const short* __restrict__ down,
                                              const int* __restrict__ lengths,
                                              const float* __restrict__ conf,
                                              short* __restrict__ cw)
{
    __shared__ char lds[81920];
    const int lg = ((blockIdx.x & 7) * 192) + (blockIdx.x >> 3);   // XCD-chunked swizzle
    const int rowblk = lg & 3;
    const int z = lg >> 2;
    const int l = z % 12;
    const int b = z / 12;
    const int tid = threadIdx.x, lane = tid & 63, w = tid >> 6;
    const int wr = w >> 2, wcg = w & 3;

    const char* Ab = (const char*)(down + (((size_t)12*BB + b)*NN + rowblk*128)*MM);
    const char* Bb = (const char*)(down + ((size_t)l*BB + b)*NN*MM);

    const char* gp[5]; int lo[5];
    #pragma unroll
    for (int q = 0; q < 5; ++q) {
        int gidx = w*5 + q;
        const char* base = (gidx < 8) ? Ab : Bb;
        int grow = ((gidx < 8) ? gidx : (gidx - 8))*16 + (lane & 15);
        gp[q] = base + (size_t)grow * MM * 2 + (lane >> 4)*16;
        lo[q] = gidx*1024 + lane*16;
    }

    f32x4 acc[4][8];
    #pragma unroll
    for (int i = 0; i < 4; ++i)
        #pragma unroll
        for (int j = 0; j < 8; ++j) { acc[i][j][0]=0.f; acc[i][j][1]=0.f; acc[i][j][2]=0.f; acc[i][j][3]=0.f; }

    auto mfma_blk = [&](int bo) {
        s16x8 af[4], bf4[8];
        #pragma unroll
        for (int i = 0; i < 4; ++i) af[i] = *(const s16x8*)(lds + bo + ((wr*4 + i)<<10) + lane*16);
        #pragma unroll
        for (int j = 0; j < 8; ++j) bf4[j] = *(const s16x8*)(lds + bo + ((8 + wcg*8 + j)<<10) + lane*16);
        #pragma unroll
        for (int i = 0; i < 4; ++i)
            #pragma unroll
            for (int j = 0; j < 8; ++j)
                acc[i][j] = __builtin_amdgcn_mfma_f32_16x16x32_bf16(af[i], bf4[j], acc[i][j], 0, 0, 0);
    };

    #pragma unroll
    for (int q = 0; q < 5; ++q) { gload16(gp[q], lds + lo[q]); gp[q] += 64; }
    __syncthreads();
    int bo = 0;
    for (int t = 1; t < 12; ++t) {
        const int nbo = bo ^ 40960;
        #pragma unroll
        for (int q = 0; q < 5; ++q) { gload16(gp[q], lds + nbo + lo[q]); gp[q] += 64; }
        mfma_blk(bo);
        __syncthreads();
        bo = nbo;
    }
    mfma_blk(bo);

    const int len = lengths[b];
    const float cf = conf[b*12 + l];

    float ps[4][4];
    #pragma unroll
    for (int i = 0; i < 4; ++i)
        #pragma unroll
        for (int r = 0; r < 4; ++r) ps[i][r] = 0.f;
    #pragma unroll
    for (int i = 0; i < 4; ++i)
        #pragma unroll
        for (int j = 0; j < 8; ++j) {
            int c = wcg*128 + j*16 + (lane & 15);
            bool keep = c < len;
            #pragma unroll
            for (int r = 0; r < 4; ++r) {
                float v = keep ? fmaxf(acc[i][j][r], 0.f) : 0.f;
                acc[i][j][r] = v;
                ps[i][r] += v;
            }
        }
    #pragma unroll
    for (int off = 1; off < 16; off <<= 1)
        #pragma unroll
        for (int i = 0; i < 4; ++i)
            #pragma unroll
            for (int r = 0; r < 4; ++r) ps[i][r] += __shfl_xor(ps[i][r], off);
    float* rs = (float*)(lds + 73728);
    if ((lane & 15) == 0) {
        #pragma unroll
        for (int i = 0; i < 4; ++i)
            #pragma unroll
            for (int r = 0; r < 4; ++r)
                rs[wcg*128 + wr*64 + i*16 + (lane >> 4)*4 + r] = ps[i][r];
    }
    __syncthreads();
    float sc[4][4];
    #pragma unroll
    for (int i = 0; i < 4; ++i)
        #pragma unroll
        for (int r = 0; r < 4; ++r) {
            int row = wr*64 + i*16 + (lane >> 4)*4 + r;
            float tot = rs[row] + rs[128 + row] + rs[256 + row] + rs[384 + row];
            sc[i][r] = cf / (tot + 1e-8f);
        }
    short* ep = (short*)(lds + w * 9216);
    short* C = cw + ((size_t)b*NN + rowblk*128 + wr*64)*K12 + (size_t)l*NN + wcg*128;
    #pragma unroll
    for (int half = 0; half < 2; ++half) {
        #pragma unroll
        for (int i = 0; i < 4; ++i)
            #pragma unroll
            for (int jj = 0; jj < 4; ++jj) {
                int j = half*4 + jj;
                int cc = jj*16 + (lane & 15);
                int cg = wcg*128 + half*64 + cc;
                #pragma unroll
                for (int r = 0; r < 4; ++r) {
                    int rr = i*16 + (lane >> 4)*4 + r;
                    float o = acc[i][j][r] * sc[i][r];
                    int ng = rowblk*128 + wr*64 + rr;
                    if (ng == cg) o += cf;
                    ep[rr*72 + cc] = f2bf_hw(o);
                }
            }
        #pragma unroll
        for (int it = 0; it < 8; ++it) {
            int cdx = it*64 + lane;
            int row = cdx >> 3, kq = cdx & 7;
            s16x8 v = *(const s16x8*)(ep + row*72 + kq*8);
            *(s16x8*)(C + (size_t)row*K12 + half*64 + kq*8) = v;
        }
    }
}

// ---------------- K7: split-K merge ----------------
__global__ __launch_bounds__(256) void k_merge(const short* __restrict__ cw,
                                               const short* __restrict__ downTb,
                                               float* __restrict__ msA,
                                               float* __restrict__ msB)
{
    __shared__ char lds[36864];
    const int lg = ((blockIdx.x & 7) * 96) + (blockIdx.x >> 3);    // XCD-chunked swizzle
    const int col0 = (lg % 3) * 128;
    const int row0 = ((lg / 3) & 3) * 128;
    const int bkh = lg / 12;
    const int b  = bkh >> 1;
    const int kh = bkh & 1;
    const char* At = (const char*)(cw     + ((size_t)b*NN + row0)*K12 + kh*3072);
    const char* Bt = (const char*)(downTb + ((size_t)b*MM + col0)*K12 + kh*3072);
    f32x4 acc[4][4]; zero_acc(acc);
    gemm_core<0>(At, nullptr, K12, Bt, K12, 3072, lds, acc);

    const int tid = threadIdx.x, lane = tid & 63, w = tid >> 6;
    const int wr = w >> 1, wc = w & 1;
    float* msH = kh ? msB : msA;
    #pragma unroll
    for (int i = 0; i < 4; ++i)
        #pragma unroll
        for (int r = 0; r < 4; ++r) {
            int grow = row0 + wr*64 + i*16 + (lane >> 4)*4 + r;
            #pragma unroll
            for (int j = 0; j < 4; ++j) {
                int gcol = col0 + wc*64 + j*16 + (lane & 15);
                msH[((size_t)b*NN + grow)*MM + gcol] = acc[i][j][r];
            }
        }
}

// ---------------- K8: proj GEMM (A = msA+msB fp32 fused, fp32 C + bias) ----------------
__global__ __launch_bounds__(256) void k_proj(const float* __restrict__ msA,
                                              const float* __restrict__ msB,
                                              const short* __restrict__ WpT,
                                              const float* __restrict__ bp,
                                              float* __restrict__ tmp)
{
    __shared__ char lds[36864];
    const int lg = ((blockIdx.x & 7) * 48) + (blockIdx.x >> 3);
    const int col0 = (lg % 3) * 128;
    const int row0 = (lg / 3) * 128;
    const char* At  = (const char*)(msA + (size_t)row0*MM);
    const char* At2 = (const char*)(msB + (size_t)row0*MM);
    const char* Bt  = (const char*)(WpT + (size_t)col0*MM);
    f32x4 acc[4][4]; zero_acc(acc);
    gemm_core<2>(At, At2, MM, Bt, MM, MM, lds, acc);

    const int tid = threadIdx.x, lane = tid & 63, w = tid >> 6;
    const int wr = w >> 1, wc = w & 1;
    float bj[4];
    #pragma unroll
    for (int j = 0; j < 4; ++j) bj[j] = bp[col0 + wc*64 + j*16 + (lane & 15)];
    #pragma unroll
    for (int i = 0; i < 4; ++i)
        #pragma unroll
        for (int r = 0; r < 4; ++r) {
            int grow = row0 + wr*64 + i*16 + (lane >> 4)*4 + r;
            #pragma unroll
            for (int j = 0; j < 4; ++j) {
                int gcol = col0 + wc*64 + j*16 + (lane & 15);
                tmp[(size_t)grow*MM + gcol] = acc[i][j][r] + bj[j];
            }
        }
}

// ---------------- K9: R = relu(anchor_feat + LN(tmp)), bf16 out ----------------
__global__ __launch_bounds__(256) void k_ln2(const float* __restrict__ tmp,
                                             const short* __restrict__ down,
                                             const float* __restrict__ g,
                                             const float* __restrict__ beta,
                                             short* __restrict__ R)
{
    const int row  = blockIdx.x*4 + (threadIdx.x >> 6);
    const int lane = threadIdx.x & 63;
    const float* p = tmp + (size_t)row*MM;
    const short* af = down + (size_t)12*BN*MM + (size_t)row*MM;
    float v[6]; float s = 0.f, s2 = 0.f;
    #pragma unroll
    for (int t = 0; t < 6; ++t) { v[t] = p[lane + t*64]; s += v[t]; s2 += v[t]*v[t]; }
    #pragma unroll
    for (int off = 32; off; off >>= 1) { s += __shfl_xor(s, off); s2 += __shfl_xor(s2, off); }
    float mu  = s * (1.f/MM);
    float inv = rsqrtf(s2 * (1.f/MM) - mu*mu + 1e-5f);
    #pragma unroll
    for (int t = 0; t < 6; ++t) {
        int m = lane + t*64;
        float o = bf2f(af[m]) + (v[t]-mu)*inv * g[m] + beta[m];
        R[(size_t)row*MM + m] = f2bf_hw(fmaxf(o, 0.f));
    }
}

// ---------------- K10: up GEMM (bf16 A, fp32 C + bias) -> d_out ----------------
__global__ __launch_bounds__(256) void k_up(const short* __restrict__ R,
                                            const short* __restrict__ WuT,
                                            const float* __restrict__ bu,
                                            float* __restrict__ Y)
{
    __shared__ char lds[32768];
    const int lg = ((blockIdx.x & 7) * 96) + (blockIdx.x >> 3);
    const int col0 = (lg % 6) * 128;
    const int row0 = (lg / 6) * 128;
    const char* At = (const char*)(R + (size_t)row0*MM);
    const char* Bt = (const char*)(WuT + (size_t)col0*MM);
    f32x4 acc[4][4]; zero_acc(acc);
    gemm_core<0>(At, nullptr, MM, Bt, MM, MM, lds, acc);

    const int tid = threadIdx.x, lane = tid & 63, w = tid >> 6;
    const int wr = w >> 1, wc = w & 1;
    float bj[4];
    #pragma unroll
    for (int j = 0; j < 4; ++j) bj[j] = bu[col0 + wc*64 + j*16 + (lane & 15)];
    #pragma unroll
    for (int i = 0; i < 4; ++i)
        #pragma unroll
        for (int r = 0; r < 4; ++r) {
            int grow = row0 + wr*64 + i*16 + (lane >> 4)*4 + r;
            #pragma unroll
            for (int j = 0; j < 4; ++j) {
                int gcol = col0 + wc*64 + j*16 + (lane & 15);
                Y[(size_t)grow*EE + gcol] = acc[i][j][r] + bj[j];
            }
        }
}

extern "C" void kernel_launch(void* const* d_in, const int* in_sizes, int n_in,
                              void* d_out, int out_size, void* d_ws, size_t ws_size,
                              hipStream_t stream)
{
    const float* X    = (const float*)d_in[0];
    const int*   len  = (const int*)  d_in[1];
    const float* Wd   = (const float*)d_in[2];
    const float* bd   = (const float*)d_in[3];
    const float* gd   = (const float*)d_in[4];
    const float* betd = (const float*)d_in[5];
    const float* Wp   = (const float*)d_in[6];
    const float* bp   = (const float*)d_in[7];
    const float* gp   = (const float*)d_in[8];
    const float* betp = (const float*)d_in[9];
    const float* Wu   = (const float*)d_in[10];
    const float* bu   = (const float*)d_in[11];
    const float* Wg   = (const float*)d_in[12];
    const float* bg   = (const float*)d_in[13];
    float* out = (float*)d_out;

    // workspace layout
    float* ws     = (float*)d_ws;
    float* tmp    = ws;                          // 6291456 f
    float* t_raw  = tmp + 6291456;               // 147456 f  (zeroed, atomic acc)
    float* a_raw  = t_raw + 147456;              // 12288 f   (zeroed, atomic acc)
    float* conf   = a_raw + 12288;               // 384 f
    short* down   = (short*)(conf + 384);        // 81788928 sh  [l][b][n][m]
    short* downTb = down   + (size_t)81788928;   // 75497472 sh  [b][m][l][n]
    short* cw     = downTb + (size_t)75497472;   // 100663296 sh [b][n][l*512+k]
    short* R      = cw     + (size_t)100663296;  // 6291456 sh
    short* WdT    = R      + (size_t)6291456;    // 3833856 sh
    short* WpT    = WdT    + (size_t)3833856;    // 147456 sh
    short* WuT    = WpT    + (size_t)147456;     // 294912 sh
    float* msA    = (float*)(WuT + 294912);      // 6291456 f
    float* msB    = msA + 6291456;               // 6291456 f

    // 0) zero the atomic accumulators; weight transposes -> bf16
    k_zero<<<156, 256, 0, stream>>>(t_raw, (147456+12288)/4);
    k_wt<<<dim3(6, 12, 13), 256, 0, stream>>>(Wd, WdT, HH, MM, (size_t)HH*MM, (size_t)HH*MM);
    k_wt<<<dim3(6, 6, 1),   256, 0, stream>>>(Wp, WpT, MM, MM, 0, 0);
    k_wt<<<dim3(12, 6, 1),  256, 0, stream>>>(Wu, WuT, MM, EE, 0, 0);
    // 1) down GEMM: 128x384 full-M tile, X read once
    k_down<<<1664, 512, 0, stream>>>(X, WdT, bd, down);
    // 2) LN in place + transposed copy + fused masked-mean raw sums
    k_ln<<<LL*BB*8, 256, 0, stream>>>(down, gd, betd, downTb, len, t_raw, a_raw);
    // 3) conf (1/len^2 folded) + lengths tail
    k_conf<<<BB, 64, 0, stream>>>(a_raw, t_raw, Wg, bg, len, conf, out);
    // 4) fused S + rowsum + normalize + conf + eye -> cw
    k_srow<<<1536, 512, 0, stream>>>(down, len, conf, cw);
    // 5) split-K merge -> fp32 halves
    k_merge<<<768, 256, 0, stream>>>(cw, downTb, msA, msB);
    // 6) proj (A = msA+msB fused)
    k_proj<<<384, 256, 0, stream>>>(msA, msB, WpT, bp, tmp);
    // 7) residual + LN + relu -> bf16
    k_ln2<<<BN/4, 256, 0, stream>>>(tmp, down, gp, betp, R);
    // 8) up -> out
    k_up<<<768, 256, 0, stream>>>(R, WuT, bu, out);
}

// Round 11
// 887.609 us; speedup vs baseline: 1.0649x; 1.0649x over previous
//
#include <hip/hip_runtime.h>

#define LL 13
#define BB 32
#define NN 512
#define HH 768
#define MM 384
#define EE 768
#define BN (BB*NN)   // 16384
#define K12 (12*NN)  // 6144

typedef __attribute__((ext_vector_type(8))) short s16x8;
typedef __attribute__((ext_vector_type(4))) float f32x4;
typedef __attribute__((ext_vector_type(4))) unsigned int u32x4;
typedef unsigned int u32;
#define AS1 __attribute__((address_space(1)))
#define AS3 __attribute__((address_space(3)))

// hardware packed fp32->bf16 (RNE), gfx950
__device__ __forceinline__ u32 cvtpk2(float a, float b) {
    u32 r; asm("v_cvt_pk_bf16_f32 %0, %1, %2" : "=v"(r) : "v"(a), "v"(b));
    return r;
}
__device__ __forceinline__ short f2bf_hw(float f) {
    u32 r; asm("v_cvt_pk_bf16_f32 %0, %1, %2" : "=v"(r) : "v"(f), "v"(f));
    return (short)r;
}
__device__ __forceinline__ float bf2f(short h) {
    union { u32 u; float f; } c; c.u = ((u32)(unsigned short)h) << 16;
    return c.f;
}
__device__ __forceinline__ void gload16(const void* g, void* l) {
    __builtin_amdgcn_global_load_lds((const AS1 u32*)g, (AS3 u32*)l, 16, 0, 0);
}

// ============ bf16 MFMA GEMM core: 128x128 tile, BK=32, 4 waves, 16x16x32 ============
// C(128x128) = A(128xK) * B^T(128xK), both operands reduction-contiguous.
// AM=0: A bf16 via global_load_lds. AM=1: A fp32 reg-staged + cvt. AM=2: A = fp32(At)+fp32(At2).
// R8-proven 2-phase double-buffered pipeline, one __syncthreads per K-step.
template<int AM>
__device__ __forceinline__ void gemm_core(const char* At, const char* At2, int lda,
                                          const char* Bt, int ldb,
                                          int K, char* lds, f32x4 acc[4][4])
{
    const int tid  = threadIdx.x;
    const int lane = tid & 63;
    const int w    = tid >> 6;
    const int mt0 = (w >> 1) * 4;
    const int nt0 = (w & 1) * 4;

    const int rg0 = (w*2)*16 + (lane & 15);
    const int rg1 = rg0 + 16;
    const int kcb = (lane >> 4) * 16;
    const char* gb0 = Bt + (size_t)rg0 * ldb * 2 + kcb;
    const char* gb1 = Bt + (size_t)rg1 * ldb * 2 + kcb;
    const int lboff0 = 8192 + (w*2)*1024;
    const int lboff1 = lboff0 + 1024;

    auto mfma_step = [&](int bo) {
        s16x8 af[4], bf4[4];
        char* sA = lds + bo;
        char* sB = sA + 8192;
        #pragma unroll
        for (int i = 0; i < 4; ++i) af[i] = *(const s16x8*)(sA + ((mt0+i)<<10) + lane*16);
        #pragma unroll
        for (int j = 0; j < 4; ++j) bf4[j] = *(const s16x8*)(sB + ((nt0+j)<<10) + lane*16);
        #pragma unroll
        for (int i = 0; i < 4; ++i)
            #pragma unroll
            for (int j = 0; j < 4; ++j)
                acc[i][j] = __builtin_amdgcn_mfma_f32_16x16x32_bf16(af[i], bf4[j], acc[i][j], 0, 0, 0);
    };

    if (AM == 0) {
        const char* ga0 = At + (size_t)rg0 * lda * 2 + kcb;
        const char* ga1 = At + (size_t)rg1 * lda * 2 + kcb;
        const int laoff0 = (w*2)*1024, laoff1 = laoff0 + 1024;
        gload16(ga0, lds + laoff0); gload16(ga1, lds + laoff1);
        gload16(gb0, lds + lboff0); gload16(gb1, lds + lboff1);
        ga0 += 64; ga1 += 64; gb0 += 64; gb1 += 64;
        __syncthreads();
        int bo = 0;
        for (int k0 = 32; k0 < K; k0 += 32) {
            const int nbo = bo ^ 16384;
            gload16(ga0, lds + nbo + laoff0); gload16(ga1, lds + nbo + laoff1);
            gload16(gb0, lds + nbo + lboff0); gload16(gb1, lds + nbo + lboff1);
            ga0 += 64; ga1 += 64; gb0 += 64; gb1 += 64;
            mfma_step(bo);
            __syncthreads();
            bo = nbo;
        }
        mfma_step(bo);
    } else {
        size_t goff_[4]; int loff_[4];
        #pragma unroll
        for (int c = 0; c < 4; ++c) {
            int id = c*256 + tid;
            int row = id >> 3, c16 = id & 7;
            goff_[c] = (size_t)row * lda * 4 + c16 * 16;
            loff_[c] = ((row>>4)*64 + (row&15) + (c16>>1)*16)*16 + (c16&1)*8;
        }
        f32x4 g[4];
        #pragma unroll
        for (int c = 0; c < 4; ++c) {
            g[c] = *(const f32x4*)(At + goff_[c]);
            if (AM == 2) {
                f32x4 h = *(const f32x4*)(At2 + goff_[c]);
                g[c][0]+=h[0]; g[c][1]+=h[1]; g[c][2]+=h[2]; g[c][3]+=h[3];
            }
        }
        gload16(gb0, lds + lboff0); gload16(gb1, lds + lboff1);
        gb0 += 64; gb1 += 64;
        #pragma unroll
        for (int c = 0; c < 4; ++c) {
            u32* d = (u32*)(lds + loff_[c]);
            d[0] = cvtpk2(g[c][0], g[c][1]);
            d[1] = cvtpk2(g[c][2], g[c][3]);
        }
        __syncthreads();
        int bo = 0;
        size_t kb = 128;
        for (int k0 = 32; k0 < K; k0 += 32, kb += 128) {
            const int nbo = bo ^ 16384;
            #pragma unroll
            for (int c = 0; c < 4; ++c) {
                g[c] = *(const f32x4*)(At + goff_[c] + kb);
                if (AM == 2) {
                    f32x4 h = *(const f32x4*)(At2 + goff_[c] + kb);
                    g[c][0]+=h[0]; g[c][1]+=h[1]; g[c][2]+=h[2]; g[c][3]+=h[3];
                }
            }
            gload16(gb0, lds + nbo + lboff0); gload16(gb1, lds + nbo + lboff1);
            gb0 += 64; gb1 += 64;
            mfma_step(bo);
            #pragma unroll
            for (int c = 0; c < 4; ++c) {
                u32* d = (u32*)(lds + nbo + loff_[c]);
                d[0] = cvtpk2(g[c][0], g[c][1]);
                d[1] = cvtpk2(g[c][2], g[c][3]);
            }
            __syncthreads();
            bo = nbo;
        }
        mfma_step(bo);
    }
}

__device__ __forceinline__ void zero_acc(f32x4 acc[4][4]) {
    #pragma unroll
    for (int i = 0; i < 4; ++i)
        #pragma unroll
        for (int j = 0; j < 4; ++j) {
            acc[i][j][0] = 0.f; acc[i][j][1] = 0.f;
            acc[i][j][2] = 0.f; acc[i][j][3] = 0.f;
        }
}

// ---------------- K0: fused weight transposes (Wd, Wp, Wu) + accumulator zeroing ----------------
// blocks 0..935: Wd[768][384] per l; 936..971: Wp[384][384]; 972..1043: Wu[384][768];
// blocks 1044..1199: zero t_raw/a_raw (159744 floats).
__global__ __launch_bounds__(256) void k_wt_all(const float* __restrict__ Wd,
                                                const float* __restrict__ Wp,
                                                const float* __restrict__ Wu,
                                                short* __restrict__ WdT,
                                                short* __restrict__ WpT,
                                                short* __restrict__ WuT,
                                                float* __restrict__ zbuf)
{
    __shared__ short L[64][80];
    const int id = blockIdx.x;
    const int t = threadIdx.x;
    if (id >= 1044) {
        int i = (id - 1044)*256 + t;
        if (i < (147456+12288)/4) { f32x4 z = {0.f,0.f,0.f,0.f}; ((f32x4*)zbuf)[i] = z; }
        return;
    }
    const float* I; short* O; int R, C, r0, c0;
    if (id < 936) {
        int z = id/72, rem = id%72;
        I = Wd + (size_t)z*HH*MM; O = WdT + (size_t)z*HH*MM;
        R = HH; C = MM; c0 = (rem%6)*64; r0 = (rem/6)*64;
    } else if (id < 972) {
        int id2 = id - 936;
        I = Wp; O = WpT; R = MM; C = MM; c0 = (id2%6)*64; r0 = (id2/6)*64;
    } else {
        int id3 = id - 972;
        I = Wu; O = WuT; R = MM; C = EE; c0 = (id3%12)*64; r0 = (id3/12)*64;
    }
    {
        int r = t >> 2, cq = (t & 3) * 16;
        const float* p = I + (size_t)(r0 + r) * C + c0 + cq;
        f32x4 u0 = *(const f32x4*)(p);
        f32x4 u1 = *(const f32x4*)(p + 4);
        f32x4 u2 = *(const f32x4*)(p + 8);
        f32x4 u3 = *(const f32x4*)(p + 12);
        u32x4 pa, pb;
        pa[0]=cvtpk2(u0[0],u0[1]); pa[1]=cvtpk2(u0[2],u0[3]);
        pa[2]=cvtpk2(u1[0],u1[1]); pa[3]=cvtpk2(u1[2],u1[3]);
        pb[0]=cvtpk2(u2[0],u2[1]); pb[1]=cvtpk2(u2[2],u2[3]);
        pb[2]=cvtpk2(u3[0],u3[1]); pb[3]=cvtpk2(u3[2],u3[3]);
        *(u32x4*)&L[r][cq]     = pa;
        *(u32x4*)&L[r][cq + 8] = pb;
    }
    __syncthreads();
    #pragma unroll
    for (int it = 0; it < 2; ++it) {
        int idd = it * 256 + t;
        int cc = idd >> 3, rq = idd & 7;
        s16x8 v;
        #pragma unroll
        for (int e = 0; e < 8; ++e) v[e] = L[rq*8 + e][cc];
        *(s16x8*)(O + (size_t)(c0 + cc) * R + r0 + rq*8) = v;
    }
}

// ---------------- K1: down GEMM (fp32 A, +bias, bf16 out pre-LN) ----------------
__global__ __launch_bounds__(256) void k_down(const float* __restrict__ X,
                                              const short* __restrict__ WdT,
                                              const float* __restrict__ bd,
                                              short* __restrict__ down)
{
    __shared__ char lds[36864];
    const int lg = ((blockIdx.x & 7) * 624) + (blockIdx.x >> 3);   // XCD-chunked swizzle
    const int col0 = (lg % 3) * 128;
    const int row0 = ((lg / 3) & 127) * 128;
    const int l = lg / 384;
    const char* At = (const char*)(X   + (size_t)l*BN*HH + (size_t)row0*HH);
    const char* Bt = (const char*)(WdT + (size_t)l*MM*HH + (size_t)col0*HH);
    f32x4 acc[4][4]; zero_acc(acc);
    gemm_core<1>(At, nullptr, HH, Bt, HH, HH, lds, acc);

    const int tid = threadIdx.x, lane = tid & 63, w = tid >> 6;
    const int wr = w >> 1, wc = w & 1;
    float bj[4];
    #pragma unroll
    for (int j = 0; j < 4; ++j) bj[j] = bd[l*MM + col0 + wc*64 + j*16 + (lane & 15)];
    __syncthreads();
    short* ep = (short*)(lds + w * 9216);
    #pragma unroll
    for (int i = 0; i < 4; ++i) {
        int rr = i*16 + (lane >> 4) * 4;
        #pragma unroll
        for (int j = 0; j < 4; ++j) {
            int cc = j*16 + (lane & 15);
            #pragma unroll
            for (int r = 0; r < 4; ++r)
                ep[(rr + r)*72 + cc] = f2bf_hw(acc[i][j][r] + bj[j]);
        }
    }
    __syncthreads();
    short* C = down + (size_t)l*BN*MM;
    #pragma unroll
    for (int it = 0; it < 8; ++it) {
        int c = it*64 + lane;
        int row = c >> 3, kq = c & 7;
        s16x8 v = *(const s16x8*)(ep + row*72 + kq*8);
        int grow = row0 + wr*64 + row;
        int gcol = col0 + wc*64 + kq*8;
        *(s16x8*)(C + (size_t)grow*MM + gcol) = v;
    }
}

// ---------------- K2: LN in place + transposed copy + fused masked-mean raw sums ----------------
__global__ __launch_bounds__(256) void k_ln(short* __restrict__ down,
                                            const float* __restrict__ g,
                                            const float* __restrict__ beta,
                                            short* __restrict__ downTb,
                                            const int* __restrict__ lengths,
                                            float* __restrict__ t_raw,
                                            float* __restrict__ a_raw)
{
    __shared__ short Lt[64][392];
    __shared__ float sacc[4][384];
    const int blk = blockIdx.x;
    const int l = blk / (BB*8);
    const int rem = blk % (BB*8);
    const int b = rem >> 3;
    const int n0 = (rem & 7) * 64;
    const int tid = threadIdx.x, lane = tid & 63, w = tid >> 6;
    const int len = lengths[b];
    float racc[6] = {0.f,0.f,0.f,0.f,0.f,0.f};

    for (int it = 0; it < 16; ++it) {
        int ri = it*4 + w;
        int n = n0 + ri;
        short* p = down + (((size_t)l*BB + b)*NN + n) * MM;
        u32* pu = (u32*)p;
        float f[6]; float s = 0.f, s2 = 0.f;
        #pragma unroll
        for (int t = 0; t < 3; ++t) {
            u32 q = pu[lane + t*64];
            float lo = bf2f((short)(q & 0xffff));
            float hi = bf2f((short)(q >> 16));
            f[2*t] = lo; f[2*t+1] = hi;
            s += lo + hi; s2 += lo*lo + hi*hi;
        }
        #pragma unroll
        for (int off = 32; off; off >>= 1) { s += __shfl_xor(s, off); s2 += __shfl_xor(s2, off); }
        float mu  = s * (1.f/MM);
        float inv = rsqrtf(s2 * (1.f/MM) - mu*mu + 1e-5f);
        const bool valid = n < len;
        #pragma unroll
        for (int t = 0; t < 3; ++t) {
            int m0 = (lane + t*64) * 2;
            float o0 = (f[2*t]  -mu)*inv * g[l*MM + m0]     + beta[l*MM + m0];
            float o1 = (f[2*t+1]-mu)*inv * g[l*MM + m0 + 1] + beta[l*MM + m0 + 1];
            u32 pk = cvtpk2(o0, o1);
            pu[lane + t*64] = pk;
            ((u32*)&Lt[ri][0])[lane + t*64] = pk;
            if (valid) { racc[2*t] += o0; racc[2*t+1] += o1; }
        }
    }
    #pragma unroll
    for (int t = 0; t < 3; ++t) {
        int m0 = (lane + t*64) * 2;
        sacc[w][m0]     = racc[2*t];
        sacc[w][m0 + 1] = racc[2*t+1];
    }
    __syncthreads();
    if (w == 0) {
        float* dst = (l == 12) ? (a_raw + b*MM) : (t_raw + ((size_t)l*BB + b)*MM);
        #pragma unroll
        for (int t = 0; t < 3; ++t) {
            #pragma unroll
            for (int e = 0; e < 2; ++e) {
                int m = (lane + t*64)*2 + e;
                float tot = sacc[0][m] + sacc[1][m] + sacc[2][m] + sacc[3][m];
                atomicAdd(&dst[m], tot);
            }
        }
    }
    if (l == 12) return;
    short* O = downTb + ((size_t)b*MM*12 + l) * NN;   // + m*12*NN + n
    #pragma unroll
    for (int it = 0; it < 12; ++it) {
        int id = it*256 + tid;
        int m = id >> 3, nq = id & 7;
        s16x8 vv;
        #pragma unroll
        for (int e = 0; e < 8; ++e) vv[e] = Lt[nq*8 + e][m];
        *(s16x8*)(O + (size_t)m*12*NN + n0 + nq*8) = vv;
    }
}

// ---------------- K4: conf from raw sums (1/len^2 folded) + lengths tail ----------------
__global__ __launch_bounds__(64) void k_conf(const float* __restrict__ a_raw,
                                             const float* __restrict__ t_raw,
                                             const float* __restrict__ Wg,
                                             const float* __restrict__ bg,
                                             const int* __restrict__ lengths,
                                             float* __restrict__ conf,
                                             float* __restrict__ out)
{
    const int b = blockIdx.x;
    const int lane = threadIdx.x;
    const float len = (float)lengths[b];
    const float inv2 = 1.f/(len*len);
    float lg[12];
    #pragma unroll
    for (int l = 0; l < 12; ++l) {
        float s = 0.f;
        #pragma unroll
        for (int t = 0; t < 6; ++t) {
            int m = lane + t*64;
            s += a_raw[b*MM + m] * t_raw[((size_t)l*BB + b)*MM + m] * Wg[m];
        }
        #pragma unroll
        for (int off = 32; off; off >>= 1) s += __shfl_xor(s, off);
        lg[l] = s * inv2 + bg[0];
    }
    float mx = lg[0];
    #pragma unroll
    for (int l = 1; l < 12; ++l) mx = fmaxf(mx, lg[l]);
    float den = 0.f, e[12];
    #pragma unroll
    for (int l = 0; l < 12; ++l) { e[l] = expf(lg[l]-mx); den += e[l]; }
    if (lane == 0) {
        #pragma unroll
        for (int l = 0; l < 12; ++l) conf[b*12 + l] = e[l]/den;
        out[(size_t)BB*NN*EE + b] = len;   // lengths tail
    }
}

// ---------------- K5: fused S row-block (dbuf K-loop, full-column store) ----------------
__global__ __launch_bounds__(512) void k_srow(const short* __restrict__ down,
                                              const int* __restrict__ lengths,
                                              const float* __restrict__ conf,
                                              short* __restrict__ cw)
{
    __shared__ char lds[81920];
    const int lg = ((blockIdx.x & 7) * 192) + (blockIdx.x >> 3);   // XCD-chunked swizzle
    const int rowblk = lg & 3;
    const int z = lg >> 2;
    const int l = z % 12;
    const int b = z / 12;
    const int tid = threadIdx.x, lane = tid & 63, w = tid >> 6;
    const int wr = w >> 2, wcg = w & 3;

    const char* Ab = (const char*)(down + (((size_t)12*BB + b)*NN + rowblk*128)*MM);
    const char* Bb = (const char*)(down + ((size_t)l*BB + b)*NN*MM);

    const char* gp[5]; int lo[5];
    #pragma unroll
    for (int q = 0; q < 5; ++q) {
        int gidx = w*5 + q;
        const char* base = (gidx < 8) ? Ab : Bb;
        int grow = ((gidx < 8) ? gidx : (gidx - 8))*16 + (lane & 15);
        gp[q] = base + (size_t)grow * MM * 2 + (lane >> 4)*16;
        lo[q] = gidx*1024 + lane*16;
    }

    f32x4 acc[4][8];
    #pragma unroll
    for (int i = 0; i < 4; ++i)
        #pragma unroll
        for (int j = 0; j < 8; ++j) { acc[i][j][0]=0.f; acc[i][j][1]=0.f; acc[i][j][2]=0.f; acc[i][j][3]=0.f; }

    auto mfma_blk = [&](int bo) {
        s16x8 af[4], bf4[8];
        #pragma unroll
        for (int i = 0; i < 4; ++i) af[i] = *(const s16x8*)(lds + bo + ((wr*4 + i)<<10) + lane*16);
        #pragma unroll
        for (int j = 0; j < 8; ++j) bf4[j] = *(const s16x8*)(lds + bo + ((8 + wcg*8 + j)<<10) + lane*16);
        #pragma unroll
        for (int i = 0; i < 4; ++i)
            #pragma unroll
            for (int j = 0; j < 8; ++j)
                acc[i][j] = __builtin_amdgcn_mfma_f32_16x16x32_bf16(af[i], bf4[j], acc[i][j], 0, 0, 0);
    };

    #pragma unroll
    for (int q = 0; q < 5; ++q) { gload16(gp[q], lds + lo[q]); gp[q] += 64; }
    __syncthreads();
    int bo = 0;
    for (int t = 1; t < 12; ++t) {
        const int nbo = bo ^ 40960;
        #pragma unroll
        for (int q = 0; q < 5; ++q) { gload16(gp[q], lds + nbo + lo[q]); gp[q] += 64; }
        mfma_blk(bo);
        __syncthreads();
        bo = nbo;
    }
    mfma_blk(bo);

    const int len = lengths[b];
    const float cf = conf[b*12 + l];

    float ps[4][4];
    #pragma unroll
    for (int i = 0; i < 4; ++i)
        #pragma unroll
        for (int r = 0; r < 4; ++r) ps[i][r] = 0.f;
    #pragma unroll
    for (int i = 0; i < 4; ++i)
        #pragma unroll
        for (int j = 0; j < 8; ++j) {
            int c = wcg*128 + j*16 + (lane & 15);
            bool keep = c < len;
            #pragma unroll
            for (int r = 0; r < 4; ++r) {
                float v = keep ? fmaxf(acc[i][j][r], 0.f) : 0.f;
                acc[i][j][r] = v;
                ps[i][r] += v;
            }
        }
    #pragma unroll
    for (int off = 1; off < 16; off <<= 1)
        #pragma unroll
        for (int i = 0; i < 4; ++i)
            #pragma unroll
            for (int r = 0; r < 4; ++r) ps[i][r] += __shfl_xor(ps[i][r], off);
    float* rs = (float*)(lds + 73728);
    if ((lane & 15) == 0) {
        #pragma unroll
        for (int i = 0; i < 4; ++i)
            #pragma unroll
            for (int r = 0; r < 4; ++r)
                rs[wcg*128 + wr*64 + i*16 + (lane >> 4)*4 + r] = ps[i][r];
    }
    __syncthreads();
    float sc[4][4];
    #pragma unroll
    for (int i = 0; i < 4; ++i)
        #pragma unroll
        for (int r = 0; r < 4; ++r) {
            int row = wr*64 + i*16 + (lane >> 4)*4 + r;
            float tot = rs[row] + rs[128 + row] + rs[256 + row] + rs[384 + row];
            sc[i][r] = cf / (tot + 1e-8f);
        }
    short* ep = (short*)(lds + w * 9216);
    short* C = cw + ((size_t)b*NN + rowblk*128 + wr*64)*K12 + (size_t)l*NN + wcg*128;
    #pragma unroll
    for (int half = 0; half < 2; ++half) {
        #pragma unroll
        for (int i = 0; i < 4; ++i)
            #pragma unroll
            for (int jj = 0; jj < 4; ++jj) {
                int j = half*4 + jj;
                int cc = jj*16 + (lane & 15);
                int cg = wcg*128 + half*64 + cc;
                #pragma unroll
                for (int r = 0; r < 4; ++r) {
                    int rr = i*16 + (lane >> 4)*4 + r;
                    float o = acc[i][j][r] * sc[i][r];
                    int ng = rowblk*128 + wr*64 + rr;
                    if (ng == cg) o += cf;
                    ep[rr*72 + cc] = f2bf_hw(o);
                }
            }
        #pragma unroll
        for (int it = 0; it < 8; ++it) {
            int cdx = it*64 + lane;
            int row = cdx >> 3, kq = cdx & 7;
            s16x8 v = *(const s16x8*)(ep + row*72 + kq*8);
            *(s16x8*)(C + (size_t)row*K12 + half*64 + kq*8) = v;
        }
    }
}

// ---------------- K7: split-K merge ----------------
__global__ __launch_bounds__(256) void k_merge(const short* __restrict__ cw,
                                               const short* __restrict__ downTb,
                                               float* __restrict__ msA,
                                               float* __restrict__ msB)
{
    __shared__ char lds[36864];
    const int lg = ((blockIdx.x & 7) * 96) + (blockIdx.x >> 3);    // XCD-chunked swizzle
    const int col0 = (lg % 3) * 128;
    const int row0 = ((lg / 3) & 3) * 128;
    const int bkh = lg / 12;
    const int b  = bkh >> 1;
    const int kh = bkh & 1;
    const char* At = (const char*)(cw     + ((size_t)b*NN + row0)*K12 + kh*3072);
    const char* Bt = (const char*)(downTb + ((size_t)b*MM + col0)*K12 + kh*3072);
    f32x4 acc[4][4]; zero_acc(acc);
    gemm_core<0>(At, nullptr, K12, Bt, K12, 3072, lds, acc);

    const int tid = threadIdx.x, lane = tid & 63, w = tid >> 6;
    const int wr = w >> 1, wc = w & 1;
    float* msH = kh ? msB : msA;
    #pragma unroll
    for (int i = 0; i < 4; ++i)
        #pragma unroll
        for (int r = 0; r < 4; ++r) {
            int grow = row0 + wr*64 + i*16 + (lane >> 4)*4 + r;
            #pragma unroll
            for (int j = 0; j < 4; ++j) {
                int gcol = col0 + wc*64 + j*16 + (lane & 15);
                msH[((size_t)b*NN + grow)*MM + gcol] = acc[i][j][r];
            }
        }
}

// ---------------- K8: proj GEMM (A = msA+msB fp32 fused, fp32 C + bias) ----------------
__global__ __launch_bounds__(256) void k_proj(const float* __restrict__ msA,
                                              const float* __restrict__ msB,
                                              const short* __restrict__ WpT,
                                              const float* __restrict__ bp,
                                              float* __restrict__ tmp)
{
    __shared__ char lds[36864];
    const int lg = ((blockIdx.x & 7) * 48) + (blockIdx.x >> 3);
    const int col0 = (lg % 3) * 128;
    const int row0 = (lg / 3) * 128;
    const char* At  = (const char*)(msA + (size_t)row0*MM);
    const char* At2 = (const char*)(msB + (size_t)row0*MM);
    const char* Bt  = (const char*)(WpT + (size_t)col0*MM);
    f32x4 acc[4][4]; zero_acc(acc);
    gemm_core<2>(At, At2, MM, Bt, MM, MM, lds, acc);

    const int tid = threadIdx.x, lane = tid & 63, w = tid >> 6;
    const int wr = w >> 1, wc = w & 1;
    float bj[4];
    #pragma unroll
    for (int j = 0; j < 4; ++j) bj[j] = bp[col0 + wc*64 + j*16 + (lane & 15)];
    #pragma unroll
    for (int i = 0; i < 4; ++i)
        #pragma unroll
        for (int r = 0; r < 4; ++r) {
            int grow = row0 + wr*64 + i*16 + (lane >> 4)*4 + r;
            #pragma unroll
            for (int j = 0; j < 4; ++j) {
                int gcol = col0 + wc*64 + j*16 + (lane & 15);
                tmp[(size_t)grow*MM + gcol] = acc[i][j][r] + bj[j];
            }
        }
}

// ---------------- K9: R = relu(anchor_feat + LN(tmp)), bf16 out ----------------
__global__ __launch_bounds__(256) void k_ln2(const float* __restrict__ tmp,
                                             const short* __restrict__ down,
                                             const float* __restrict__ g,
                                             const float* __restrict__ beta,
                                             short* __restrict__ R)
{
    const int row  = blockIdx.x*4 + (threadIdx.x >> 6);
    const int lane = threadIdx.x & 63;
    const float* p = tmp + (size_t)row*MM;
    const short* af = down + (size_t)12*BN*MM + (size_t)row*MM;
    float v[6]; float s = 0.f, s2 = 0.f;
    #pragma unroll
    for (int t = 0; t < 6; ++t) { v[t] = p[lane + t*64]; s += v[t]; s2 += v[t]*v[t]; }
    #pragma unroll
    for (int off = 32; off; off >>= 1) { s += __shfl_xor(s, off); s2 += __shfl_xor(s2, off); }
    float mu  = s * (1.f/MM);
    float inv = rsqrtf(s2 * (1.f/MM) - mu*mu + 1e-5f);
    #pragma unroll
    for (int t = 0; t < 6; ++t) {
        int m = lane + t*64;
        float o = bf2f(af[m]) + (v[t]-mu)*inv * g[m] + beta[m];
        R[(size_t)row*MM + m] = f2bf_hw(fmaxf(o, 0.f));
    }
}

// ---------------- K10: up GEMM (bf16 A, fp32 C + bias) -> d_out ----------------
__global__ __launch_bounds__(256) void k_up(const short* __restrict__ R,
                                            const short* __restrict__ WuT,
                                            const float* __restrict__ bu,
                                            float* __restrict__ Y)
{
    __shared__ char lds[32768];
    const int lg = ((blockIdx.x & 7) * 96) + (blockIdx.x >> 3);
    const int col0 = (lg % 6) * 128;
    const int row0 = (lg / 6) * 128;
    const char* At = (const char*)(R + (size_t)row0*MM);
    const char* Bt = (const char*)(WuT + (size_t)col0*MM);
    f32x4 acc[4][4]; zero_acc(acc);
    gemm_core<0>(At, nullptr, MM, Bt, MM, MM, lds, acc);

    const int tid = threadIdx.x, lane = tid & 63, w = tid >> 6;
    const int wr = w >> 1, wc = w & 1;
    float bj[4];
    #pragma unroll
    for (int j = 0; j < 4; ++j) bj[j] = bu[col0 + wc*64 + j*16 + (lane & 15)];
    #pragma unroll
    for (int i = 0; i < 4; ++i)
        #pragma unroll
        for (int r = 0; r < 4; ++r) {
            int grow = row0 + wr*64 + i*16 + (lane >> 4)*4 + r;
            #pragma unroll
            for (int j = 0; j < 4; ++j) {
                int gcol = col0 + wc*64 + j*16 + (lane & 15);
                Y[(size_t)grow*EE + gcol] = acc[i][j][r] + bj[j];
            }
        }
}

extern "C" void kernel_launch(void* const* d_in, const int* in_sizes, int n_in,
                              void* d_out, int out_size, void* d_ws, size_t ws_size,
                              hipStream_t stream)
{
    const float* X    = (const float*)d_in[0];
    const int*   len  = (const int*)  d_in[1];
    const float* Wd   = (const float*)d_in[2];
    const float* bd   = (const float*)d_in[3];
    const float* gd   = (const float*)d_in[4];
    const float* betd = (const float*)d_in[5];
    const float* Wp   = (const float*)d_in[6];
    const float* bp   = (const float*)d_in[7];
    const float* gp   = (const float*)d_in[8];
    const float* betp = (const float*)d_in[9];
    const float* Wu   = (const float*)d_in[10];
    const float* bu   = (const float*)d_in[11];
    const float* Wg   = (const float*)d_in[12];
    const float* bg   = (const float*)d_in[13];
    float* out = (float*)d_out;

    // workspace layout
    float* ws     = (float*)d_ws;
    float* tmp    = ws;                          // 6291456 f
    float* t_raw  = tmp + 6291456;               // 147456 f  (zeroed, atomic acc)
    float* a_raw  = t_raw + 147456;              // 12288 f   (zeroed, atomic acc)
    float* conf   = a_raw + 12288;               // 384 f
    short* down   = (short*)(conf + 384);        // 81788928 sh  [l][b][n][m]
    short* downTb = down   + (size_t)81788928;   // 75497472 sh  [b][m][l][n]
    short* cw     = downTb + (size_t)75497472;   // 100663296 sh [b][n][l*512+k]
    short* R      = cw     + (size_t)100663296;  // 6291456 sh
    short* WdT    = R      + (size_t)6291456;    // 3833856 sh
    short* WpT    = WdT    + (size_t)3833856;    // 147456 sh
    short* WuT    = WpT    + (size_t)147456;     // 294912 sh
    float* msA    = (float*)(WuT + 294912);      // 6291456 f
    float* msB    = msA + 6291456;               // 6291456 f

    // 0) fused weight transposes + accumulator zeroing
    k_wt_all<<<1200, 256, 0, stream>>>(Wd, Wp, Wu, WdT, WpT, WuT, t_raw);
    // 1) down GEMM (R8 128x128 structure)
    k_down<<<4992, 256, 0, stream>>>(X, WdT, bd, down);
    // 2) LN in place + transposed copy + fused masked-mean raw sums
    k_ln<<<LL*BB*8, 256, 0, stream>>>(down, gd, betd, downTb, len, t_raw, a_raw);
    // 3) conf (1/len^2 folded) + lengths tail
    k_conf<<<BB, 64, 0, stream>>>(a_raw, t_raw, Wg, bg, len, conf, out);
    // 4) fused S + rowsum + normalize + conf + eye -> cw
    k_srow<<<1536, 512, 0, stream>>>(down, len, conf, cw);
    // 5) split-K merge -> fp32 halves
    k_merge<<<768, 256, 0, stream>>>(cw, downTb, msA, msB);
    // 6) proj (A = msA+msB fused)
    k_proj<<<384, 256, 0, stream>>>(msA, msB, WpT, bp, tmp);
    // 7) residual + LN + relu -> bf16
    k_ln2<<<BN/4, 256, 0, stream>>>(tmp, down, gp, betp, R);
    // 8) up -> out
    k_up<<<768, 256, 0, stream>>>(R, WuT, bu, out);
}